// Round 4
// baseline (249.410 us; speedup 1.0000x reference)
//
#include <hip/hip_runtime.h>
#include <math.h>

// Volume dims (fixed by the problem: IMG_SHAPE = (256,256,256))
#define DD 256
#define HH 256
#define WW 256

// ---------------------------------------------------------------------------
// Kernel 1: one thread computes the 3x4 resampling transform
// T = rows 0..2 of inv(flo_v2r) @ T_rig @ ref_v2r -> 12 floats in d_ws.
// Runs once (~1-3 us); keeps the ~600-op transform OFF the per-block path
// of the warp kernel (R3 post-mortem: fusing it cost ~50 us of VALU issue).
// ---------------------------------------------------------------------------
__global__ void compute_T_kernel(const float* __restrict__ angle,
                                 const float* __restrict__ trans,
                                 const float* __restrict__ ref_v2r,
                                 const float* __restrict__ flo_v2r,
                                 const float* __restrict__ cog,
                                 float* __restrict__ Tout /* 12 floats */) {
    if (blockIdx.x != 0 || threadIdx.x != 0) return;

    const float ax = angle[0], ay = angle[1], az = angle[2];
    const float cx = cosf(ax), sx = sinf(ax);
    const float cy = cosf(ay), sy = sinf(ay);
    const float cz = cosf(az), sz = sinf(az);

    // R = Rx @ Ry @ Rz ;  Rx@Ry = [[cy,0,sy],[sx*sy,cx,-sx*cy],[-cx*sy,sx,cx*cy]]
    float R[3][3];
    const float a00 = cy,       a01 = 0.0f, a02 = sy;
    const float a10 = sx * sy,  a11 = cx,   a12 = -sx * cy;
    const float a20 = -cx * sy, a21 = sx,   a22 = cx * cy;
    R[0][0] = a00 * cz + a01 * sz; R[0][1] = -a00 * sz + a01 * cz; R[0][2] = a02;
    R[1][0] = a10 * cz + a11 * sz; R[1][1] = -a10 * sz + a11 * cz; R[1][2] = a12;
    R[2][0] = a20 * cz + a21 * sz; R[2][1] = -a20 * sz + a21 * cz; R[2][2] = a22;

    // T_rig: linear part R, translation cog + t - R@cog
    float Trig[4][4];
    for (int r = 0; r < 4; ++r)
        for (int c = 0; c < 4; ++c)
            Trig[r][c] = (r == c) ? 1.0f : 0.0f;
    for (int r = 0; r < 3; ++r) {
        for (int c = 0; c < 3; ++c) Trig[r][c] = R[r][c];
        Trig[r][3] = cog[r] + trans[r]
                   - (R[r][0] * cog[0] + R[r][1] * cog[1] + R[r][2] * cog[2]);
    }

    // Closed-form 4x4 inverse of flo_v2r (adjugate).
    float m[16], inv[16];
    for (int q = 0; q < 16; ++q) m[q] = flo_v2r[q];
    inv[0]  =  m[5]*m[10]*m[15] - m[5]*m[11]*m[14] - m[9]*m[6]*m[15]
             + m[9]*m[7]*m[14] + m[13]*m[6]*m[11] - m[13]*m[7]*m[10];
    inv[4]  = -m[4]*m[10]*m[15] + m[4]*m[11]*m[14] + m[8]*m[6]*m[15]
             - m[8]*m[7]*m[14] - m[12]*m[6]*m[11] + m[12]*m[7]*m[10];
    inv[8]  =  m[4]*m[9]*m[15] - m[4]*m[11]*m[13] - m[8]*m[5]*m[15]
             + m[8]*m[7]*m[13] + m[12]*m[5]*m[11] - m[12]*m[7]*m[9];
    inv[12] = -m[4]*m[9]*m[14] + m[4]*m[10]*m[13] + m[8]*m[5]*m[14]
             - m[8]*m[6]*m[13] - m[12]*m[5]*m[10] + m[12]*m[6]*m[9];
    inv[1]  = -m[1]*m[10]*m[15] + m[1]*m[11]*m[14] + m[9]*m[2]*m[15]
             - m[9]*m[3]*m[14] - m[13]*m[2]*m[11] + m[13]*m[3]*m[10];
    inv[5]  =  m[0]*m[10]*m[15] - m[0]*m[11]*m[14] - m[8]*m[2]*m[15]
             + m[8]*m[3]*m[14] + m[12]*m[2]*m[11] - m[12]*m[3]*m[10];
    inv[9]  = -m[0]*m[9]*m[15] + m[0]*m[11]*m[13] + m[8]*m[1]*m[15]
             - m[8]*m[3]*m[13] - m[12]*m[1]*m[11] + m[12]*m[3]*m[9];
    inv[13] =  m[0]*m[9]*m[14] - m[0]*m[10]*m[13] - m[8]*m[1]*m[14]
             + m[8]*m[2]*m[13] + m[12]*m[1]*m[10] - m[12]*m[2]*m[9];
    inv[2]  =  m[1]*m[6]*m[15] - m[1]*m[7]*m[14] - m[5]*m[2]*m[15]
             + m[5]*m[3]*m[14] + m[13]*m[2]*m[7] - m[13]*m[3]*m[6];
    inv[6]  = -m[0]*m[6]*m[15] + m[0]*m[7]*m[14] + m[4]*m[2]*m[15]
             - m[4]*m[3]*m[14] - m[12]*m[2]*m[7] + m[12]*m[3]*m[6];
    inv[10] =  m[0]*m[5]*m[15] - m[0]*m[7]*m[13] - m[4]*m[1]*m[15]
             + m[4]*m[3]*m[13] + m[12]*m[1]*m[7] - m[12]*m[3]*m[5];
    inv[14] = -m[0]*m[5]*m[14] + m[0]*m[6]*m[13] + m[4]*m[1]*m[14]
             - m[4]*m[2]*m[13] - m[12]*m[1]*m[6] + m[12]*m[2]*m[5];
    inv[3]  = -m[1]*m[6]*m[11] + m[1]*m[7]*m[10] + m[5]*m[2]*m[11]
             - m[5]*m[3]*m[10] - m[9]*m[2]*m[7] + m[9]*m[3]*m[6];
    inv[7]  =  m[0]*m[6]*m[11] - m[0]*m[7]*m[10] - m[4]*m[2]*m[11]
             + m[4]*m[3]*m[10] + m[8]*m[2]*m[7] - m[8]*m[3]*m[6];
    inv[11] = -m[0]*m[5]*m[11] + m[0]*m[7]*m[9] + m[4]*m[1]*m[11]
             - m[4]*m[3]*m[9] - m[8]*m[1]*m[7] + m[8]*m[3]*m[5];
    inv[15] =  m[0]*m[5]*m[10] - m[0]*m[6]*m[9] - m[4]*m[1]*m[10]
             + m[4]*m[2]*m[9] + m[8]*m[1]*m[6] - m[8]*m[2]*m[5];
    const float det = m[0]*inv[0] + m[1]*inv[4] + m[2]*inv[8] + m[3]*inv[12];
    const float rdet = 1.0f / det;

    // M1 = Trig @ ref_v2r ; T = invF @ M1 ; rows 0..2 out
    float M1[4][4];
    for (int r = 0; r < 4; ++r)
        for (int c = 0; c < 4; ++c) {
            float s = 0.0f;
            for (int q = 0; q < 4; ++q) s += Trig[r][q] * ref_v2r[q * 4 + c];
            M1[r][c] = s;
        }
    for (int r = 0; r < 3; ++r)
        for (int c = 0; c < 4; ++c) {
            float s = 0.0f;
            for (int q = 0; q < 4; ++q) s += (inv[r * 4 + q] * rdet) * M1[q][c];
            Tout[r * 4 + c] = s;
        }
}

// ---------------------------------------------------------------------------
// Kernel 2: trilinear warp. T is read with wave-uniform (scalar) loads — no
// LDS, no barrier. XCD-aware brick mapping (bid&7 -> 2x2x2 brick of 128^3)
// keeps each XCD's L2 on its own ~15 MB brick+halo (R3: FETCH 232->36 MB).
// Nontemporal stores keep the 64 MB write stream out of L2.
// ---------------------------------------------------------------------------
__global__ __launch_bounds__(256) void warp_kernel(
        const float* __restrict__ vol,
        const float* __restrict__ T,
        float* __restrict__ out) {
    // Uniform loads (no threadIdx dependence) -> s_load, broadcast via SGPRs.
    const float t0 = T[0],  t1 = T[1],  t2  = T[2],  t3  = T[3];
    const float t4 = T[4],  t5 = T[5],  t6  = T[6],  t7  = T[7];
    const float t8 = T[8],  t9 = T[9],  t10 = T[10], t11 = T[11];

    const int bid = blockIdx.x;
    const int xcd = bid & 7;
    const int n = bid >> 3;          // 0..8191 per brick
    const int bi = (xcd >> 2) & 1;
    const int bj = (xcd >> 1) & 1;
    const int bk = xcd & 1;
    const int kt = n & 1;            // 2 k-tiles of 64
    const int jt = (n >> 1) & 31;    // 32 j-tiles of 4
    const int it = n >> 6;           // 128 i-planes

    const int tx = threadIdx.x & 63; // k within tile (wave = contiguous k)
    const int ty = threadIdx.x >> 6; // j within tile

    const int i = (bi << 7) + it;
    const int j = (bj << 7) + (jt << 2) + ty;
    const int k = (bk << 7) + (kt << 6) + tx;

    const float gi = (float)i, gj = (float)j, gk = (float)k;
    float di = t0 * gi + t1 * gj + t2  * gk + t3;
    float dj = t4 * gi + t5 * gj + t6  * gk + t7;
    float dk = t8 * gi + t9 * gj + t10 * gk + t11;

    const bool ok = (di >= 0.0f) & (di <= (float)(DD - 1)) &
                    (dj >= 0.0f) & (dj <= (float)(HH - 1)) &
                    (dk >= 0.0f) & (dk <= (float)(WW - 1));

    di = fminf(fmaxf(di, 0.0f), (float)(DD - 1));
    dj = fminf(fmaxf(dj, 0.0f), (float)(HH - 1));
    dk = fminf(fmaxf(dk, 0.0f), (float)(WW - 1));

    const int fi = (int)di;
    const int fj = (int)dj;
    const int fk = (int)dk;
    const int ci = min(fi + 1, DD - 1);
    const int cj = min(fj + 1, HH - 1);
    const int ck = min(fk + 1, WW - 1);

    const float wi = di - (float)fi;
    const float wj = dj - (float)fj;
    const float wk = dk - (float)fk;

    const int fi_o = fi << 16, ci_o = ci << 16;
    const int fj_o = fj << 8,  cj_o = cj << 8;

    const float v000 = vol[fi_o + fj_o + fk];
    const float v001 = vol[fi_o + fj_o + ck];
    const float v010 = vol[fi_o + cj_o + fk];
    const float v011 = vol[fi_o + cj_o + ck];
    const float v100 = vol[ci_o + fj_o + fk];
    const float v101 = vol[ci_o + fj_o + ck];
    const float v110 = vol[ci_o + cj_o + fk];
    const float v111 = vol[ci_o + cj_o + ck];

    // nested lerp: along k, then j, then i
    const float c00 = v000 + (v001 - v000) * wk;
    const float c01 = v010 + (v011 - v010) * wk;
    const float c10 = v100 + (v101 - v100) * wk;
    const float c11 = v110 + (v111 - v110) * wk;
    const float c0  = c00 + (c01 - c00) * wj;
    const float c1  = c10 + (c11 - c10) * wj;
    const float val = c0 + (c1 - c0) * wi;

    __builtin_nontemporal_store(ok ? val : 0.0f, &out[(i << 16) + (j << 8) + k]);
}

extern "C" void kernel_launch(void* const* d_in, const int* in_sizes, int n_in,
                              void* d_out, int out_size, void* d_ws, size_t ws_size,
                              hipStream_t stream) {
    const float* image_targ  = (const float*)d_in[0];
    const float* angle       = (const float*)d_in[1];
    const float* translation = (const float*)d_in[2];
    const float* ref_v2r     = (const float*)d_in[3];
    const float* flo_v2r     = (const float*)d_in[4];
    const float* cog         = (const float*)d_in[5];
    float* out = (float*)d_out;
    float* Tws = (float*)d_ws;   // 12 floats

    compute_T_kernel<<<1, 64, 0, stream>>>(angle, translation, ref_v2r,
                                           flo_v2r, cog, Tws);
    warp_kernel<<<DD * HH, 256, 0, stream>>>(image_targ, Tws, out);
}

// Round 5
// 249.265 us; speedup vs baseline: 1.0006x; 1.0006x over previous
//
#include <hip/hip_runtime.h>
#include <math.h>

// Volume dims (fixed by the problem: IMG_SHAPE = (256,256,256))
#define DD 256
#define HH 256
#define WW 256
#define IPT 8   // output voxels per thread (along i)

// ---------------------------------------------------------------------------
// Kernel 1: one thread computes the 3x4 resampling transform
// T = rows 0..2 of inv(flo_v2r) @ T_rig @ ref_v2r -> 12 floats in d_ws.
// ---------------------------------------------------------------------------
__global__ void compute_T_kernel(const float* __restrict__ angle,
                                 const float* __restrict__ trans,
                                 const float* __restrict__ ref_v2r,
                                 const float* __restrict__ flo_v2r,
                                 const float* __restrict__ cog,
                                 float* __restrict__ Tout /* 12 floats */) {
    if (blockIdx.x != 0 || threadIdx.x != 0) return;

    const float ax = angle[0], ay = angle[1], az = angle[2];
    const float cx = cosf(ax), sx = sinf(ax);
    const float cy = cosf(ay), sy = sinf(ay);
    const float cz = cosf(az), sz = sinf(az);

    // R = Rx @ Ry @ Rz ;  Rx@Ry = [[cy,0,sy],[sx*sy,cx,-sx*cy],[-cx*sy,sx,cx*cy]]
    float R[3][3];
    const float a00 = cy,       a01 = 0.0f, a02 = sy;
    const float a10 = sx * sy,  a11 = cx,   a12 = -sx * cy;
    const float a20 = -cx * sy, a21 = sx,   a22 = cx * cy;
    R[0][0] = a00 * cz + a01 * sz; R[0][1] = -a00 * sz + a01 * cz; R[0][2] = a02;
    R[1][0] = a10 * cz + a11 * sz; R[1][1] = -a10 * sz + a11 * cz; R[1][2] = a12;
    R[2][0] = a20 * cz + a21 * sz; R[2][1] = -a20 * sz + a21 * cz; R[2][2] = a22;

    // T_rig: linear part R, translation cog + t - R@cog
    float Trig[4][4];
    for (int r = 0; r < 4; ++r)
        for (int c = 0; c < 4; ++c)
            Trig[r][c] = (r == c) ? 1.0f : 0.0f;
    for (int r = 0; r < 3; ++r) {
        for (int c = 0; c < 3; ++c) Trig[r][c] = R[r][c];
        Trig[r][3] = cog[r] + trans[r]
                   - (R[r][0] * cog[0] + R[r][1] * cog[1] + R[r][2] * cog[2]);
    }

    // Closed-form 4x4 inverse of flo_v2r (adjugate).
    float m[16], inv[16];
    for (int q = 0; q < 16; ++q) m[q] = flo_v2r[q];
    inv[0]  =  m[5]*m[10]*m[15] - m[5]*m[11]*m[14] - m[9]*m[6]*m[15]
             + m[9]*m[7]*m[14] + m[13]*m[6]*m[11] - m[13]*m[7]*m[10];
    inv[4]  = -m[4]*m[10]*m[15] + m[4]*m[11]*m[14] + m[8]*m[6]*m[15]
             - m[8]*m[7]*m[14] - m[12]*m[6]*m[11] + m[12]*m[7]*m[10];
    inv[8]  =  m[4]*m[9]*m[15] - m[4]*m[11]*m[13] - m[8]*m[5]*m[15]
             + m[8]*m[7]*m[13] + m[12]*m[5]*m[11] - m[12]*m[7]*m[9];
    inv[12] = -m[4]*m[9]*m[14] + m[4]*m[10]*m[13] + m[8]*m[5]*m[14]
             - m[8]*m[6]*m[13] - m[12]*m[5]*m[10] + m[12]*m[6]*m[9];
    inv[1]  = -m[1]*m[10]*m[15] + m[1]*m[11]*m[14] + m[9]*m[2]*m[15]
             - m[9]*m[3]*m[14] - m[13]*m[2]*m[11] + m[13]*m[3]*m[10];
    inv[5]  =  m[0]*m[10]*m[15] - m[0]*m[11]*m[14] - m[8]*m[2]*m[15]
             + m[8]*m[3]*m[14] + m[12]*m[2]*m[11] - m[12]*m[3]*m[10];
    inv[9]  = -m[0]*m[9]*m[15] + m[0]*m[11]*m[13] + m[8]*m[1]*m[15]
             - m[8]*m[3]*m[13] - m[12]*m[1]*m[11] + m[12]*m[3]*m[9];
    inv[13] =  m[0]*m[9]*m[14] - m[0]*m[10]*m[13] - m[8]*m[1]*m[14]
             + m[8]*m[2]*m[13] + m[12]*m[1]*m[10] - m[12]*m[2]*m[9];
    inv[2]  =  m[1]*m[6]*m[15] - m[1]*m[7]*m[14] - m[5]*m[2]*m[15]
             + m[5]*m[3]*m[14] + m[13]*m[2]*m[7] - m[13]*m[3]*m[6];
    inv[6]  = -m[0]*m[6]*m[15] + m[0]*m[7]*m[14] + m[4]*m[2]*m[15]
             - m[4]*m[3]*m[14] - m[12]*m[2]*m[7] + m[12]*m[3]*m[6];
    inv[10] =  m[0]*m[5]*m[15] - m[0]*m[7]*m[13] - m[4]*m[1]*m[15]
             + m[4]*m[3]*m[13] + m[12]*m[1]*m[7] - m[12]*m[3]*m[5];
    inv[14] = -m[0]*m[5]*m[14] + m[0]*m[6]*m[13] + m[4]*m[1]*m[14]
             - m[4]*m[2]*m[13] - m[12]*m[1]*m[6] + m[12]*m[2]*m[5];
    inv[3]  = -m[1]*m[6]*m[11] + m[1]*m[7]*m[10] + m[5]*m[2]*m[11]
             - m[5]*m[3]*m[10] - m[9]*m[2]*m[7] + m[9]*m[3]*m[6];
    inv[7]  =  m[0]*m[6]*m[11] - m[0]*m[7]*m[10] - m[4]*m[2]*m[11]
             + m[4]*m[3]*m[10] + m[8]*m[2]*m[7] - m[8]*m[3]*m[6];
    inv[11] = -m[0]*m[5]*m[11] + m[0]*m[7]*m[9] + m[4]*m[1]*m[11]
             - m[4]*m[3]*m[9] - m[8]*m[1]*m[7] + m[8]*m[3]*m[5];
    inv[15] =  m[0]*m[5]*m[10] - m[0]*m[6]*m[9] - m[4]*m[1]*m[10]
             + m[4]*m[2]*m[9] + m[8]*m[1]*m[6] - m[8]*m[2]*m[5];
    const float det = m[0]*inv[0] + m[1]*inv[4] + m[2]*inv[8] + m[3]*inv[12];
    const float rdet = 1.0f / det;

    // M1 = Trig @ ref_v2r ; T = invF @ M1 ; rows 0..2 out
    float M1[4][4];
    for (int r = 0; r < 4; ++r)
        for (int c = 0; c < 4; ++c) {
            float s = 0.0f;
            for (int q = 0; q < 4; ++q) s += Trig[r][q] * ref_v2r[q * 4 + c];
            M1[r][c] = s;
        }
    for (int r = 0; r < 3; ++r)
        for (int c = 0; c < 4; ++c) {
            float s = 0.0f;
            for (int q = 0; q < 4; ++q) s += (inv[r * 4 + q] * rdet) * M1[q][c];
            Tout[r * 4 + c] = s;
        }
}

// ---------------------------------------------------------------------------
// Kernel 2: trilinear warp, IPT=8 output voxels per thread (a column along i).
// R4 post-mortem: single-voxel threads were latency/short-wave bound (all
// pipes <30%). Multi-voxel threads amortize wave setup and put ~64 loads in
// flight per wave. Coordinates update incrementally (+T[r][0] per i-step).
// XCD-aware brick mapping kept (FETCH 232->36 MB in R3). Nontemporal stores.
// ---------------------------------------------------------------------------
__global__ __launch_bounds__(256) void warp_kernel(
        const float* __restrict__ vol,
        const float* __restrict__ T,
        float* __restrict__ out) {
    // Wave-uniform scalar loads of the transform.
    const float t0 = T[0],  t1 = T[1],  t2  = T[2],  t3  = T[3];
    const float t4 = T[4],  t5 = T[5],  t6  = T[6],  t7  = T[7];
    const float t8 = T[8],  t9 = T[9],  t10 = T[10], t11 = T[11];

    // Brick mapping: xcd -> 2x2x2 brick of 128^3. Within a brick:
    // n = kt(2) x jt(32) x it(16); each thread does IPT=8 i-planes.
    const int bid = blockIdx.x;
    const int xcd = bid & 7;
    const int n = bid >> 3;          // 0..1023 per brick
    const int bi = (xcd >> 2) & 1;
    const int bj = (xcd >> 1) & 1;
    const int bk = xcd & 1;
    const int kt = n & 1;            // 2 k-tiles of 64
    const int jt = (n >> 1) & 31;    // 32 j-tiles of 4
    const int it = n >> 6;           // 16 i-tiles of IPT

    const int tx = threadIdx.x & 63; // k within tile (wave = contiguous k)
    const int ty = threadIdx.x >> 6; // j within tile

    const int i0 = (bi << 7) + it * IPT;
    const int j  = (bj << 7) + (jt << 2) + ty;
    const int k  = (bk << 7) + (kt << 6) + tx;

    const float gj = (float)j, gk = (float)k;
    float di = t0 * (float)i0 + t1 * gj + t2  * gk + t3;
    float dj = t4 * (float)i0 + t5 * gj + t6  * gk + t7;
    float dk = t8 * (float)i0 + t9 * gj + t10 * gk + t11;

    const int out_base = (i0 << 16) + (j << 8) + k;

#pragma unroll
    for (int s = 0; s < IPT; ++s) {
        const bool ok = (di >= 0.0f) & (di <= (float)(DD - 1)) &
                        (dj >= 0.0f) & (dj <= (float)(HH - 1)) &
                        (dk >= 0.0f) & (dk <= (float)(WW - 1));

        const float cdi = fminf(fmaxf(di, 0.0f), (float)(DD - 1));
        const float cdj = fminf(fmaxf(dj, 0.0f), (float)(HH - 1));
        const float cdk = fminf(fmaxf(dk, 0.0f), (float)(WW - 1));

        const int fi = (int)cdi;
        const int fj = (int)cdj;
        const int fk = (int)cdk;
        const int ci = min(fi + 1, DD - 1);
        const int cj = min(fj + 1, HH - 1);
        const int ck = min(fk + 1, WW - 1);

        const float wi = cdi - (float)fi;
        const float wj = cdj - (float)fj;
        const float wk = cdk - (float)fk;

        const int fi_o = fi << 16, ci_o = ci << 16;
        const int fj_o = fj << 8,  cj_o = cj << 8;

        const float v000 = vol[fi_o + fj_o + fk];
        const float v001 = vol[fi_o + fj_o + ck];
        const float v010 = vol[fi_o + cj_o + fk];
        const float v011 = vol[fi_o + cj_o + ck];
        const float v100 = vol[ci_o + fj_o + fk];
        const float v101 = vol[ci_o + fj_o + ck];
        const float v110 = vol[ci_o + cj_o + fk];
        const float v111 = vol[ci_o + cj_o + ck];

        const float c00 = v000 + (v001 - v000) * wk;
        const float c01 = v010 + (v011 - v010) * wk;
        const float c10 = v100 + (v101 - v100) * wk;
        const float c11 = v110 + (v111 - v110) * wk;
        const float c0  = c00 + (c01 - c00) * wj;
        const float c1  = c10 + (c11 - c10) * wj;
        const float val = c0 + (c1 - c0) * wi;

        __builtin_nontemporal_store(ok ? val : 0.0f,
                                    &out[out_base + (s << 16)]);

        di += t0;
        dj += t4;
        dk += t8;
    }
}

extern "C" void kernel_launch(void* const* d_in, const int* in_sizes, int n_in,
                              void* d_out, int out_size, void* d_ws, size_t ws_size,
                              hipStream_t stream) {
    const float* image_targ  = (const float*)d_in[0];
    const float* angle       = (const float*)d_in[1];
    const float* translation = (const float*)d_in[2];
    const float* ref_v2r     = (const float*)d_in[3];
    const float* flo_v2r     = (const float*)d_in[4];
    const float* cog         = (const float*)d_in[5];
    float* out = (float*)d_out;
    float* Tws = (float*)d_ws;   // 12 floats

    compute_T_kernel<<<1, 64, 0, stream>>>(angle, translation, ref_v2r,
                                           flo_v2r, cog, Tws);
    warp_kernel<<<(DD * HH) / IPT, 256, 0, stream>>>(image_targ, Tws, out);
}

// Round 6
// 175.823 us; speedup vs baseline: 1.4185x; 1.4177x over previous
//
#include <hip/hip_runtime.h>
#include <math.h>

// Volume dims (fixed by the problem: IMG_SHAPE = (256,256,256))
#define DD 256
#define HH 256
#define WW 256
#define IPT 8   // output voxels per thread (along i)

// float2 with 4-byte alignment: lets us load a k-adjacent corner PAIR with a
// single global_load_dwordx2 at any dword-aligned address (gfx950 supports
// unaligned multi-dword global loads).
typedef float f2v __attribute__((ext_vector_type(2)));
typedef f2v __attribute__((aligned(4))) f2u;

// ---------------------------------------------------------------------------
// Kernel 1: one thread computes the 3x4 resampling transform
// T = rows 0..2 of inv(flo_v2r) @ T_rig @ ref_v2r -> 12 floats in d_ws.
// ---------------------------------------------------------------------------
__global__ void compute_T_kernel(const float* __restrict__ angle,
                                 const float* __restrict__ trans,
                                 const float* __restrict__ ref_v2r,
                                 const float* __restrict__ flo_v2r,
                                 const float* __restrict__ cog,
                                 float* __restrict__ Tout /* 12 floats */) {
    if (blockIdx.x != 0 || threadIdx.x != 0) return;

    const float ax = angle[0], ay = angle[1], az = angle[2];
    const float cx = cosf(ax), sx = sinf(ax);
    const float cy = cosf(ay), sy = sinf(ay);
    const float cz = cosf(az), sz = sinf(az);

    // R = Rx @ Ry @ Rz ;  Rx@Ry = [[cy,0,sy],[sx*sy,cx,-sx*cy],[-cx*sy,sx,cx*cy]]
    float R[3][3];
    const float a00 = cy,       a01 = 0.0f, a02 = sy;
    const float a10 = sx * sy,  a11 = cx,   a12 = -sx * cy;
    const float a20 = -cx * sy, a21 = sx,   a22 = cx * cy;
    R[0][0] = a00 * cz + a01 * sz; R[0][1] = -a00 * sz + a01 * cz; R[0][2] = a02;
    R[1][0] = a10 * cz + a11 * sz; R[1][1] = -a10 * sz + a11 * cz; R[1][2] = a12;
    R[2][0] = a20 * cz + a21 * sz; R[2][1] = -a20 * sz + a21 * cz; R[2][2] = a22;

    // T_rig: linear part R, translation cog + t - R@cog
    float Trig[4][4];
    for (int r = 0; r < 4; ++r)
        for (int c = 0; c < 4; ++c)
            Trig[r][c] = (r == c) ? 1.0f : 0.0f;
    for (int r = 0; r < 3; ++r) {
        for (int c = 0; c < 3; ++c) Trig[r][c] = R[r][c];
        Trig[r][3] = cog[r] + trans[r]
                   - (R[r][0] * cog[0] + R[r][1] * cog[1] + R[r][2] * cog[2]);
    }

    // Closed-form 4x4 inverse of flo_v2r (adjugate).
    float m[16], inv[16];
    for (int q = 0; q < 16; ++q) m[q] = flo_v2r[q];
    inv[0]  =  m[5]*m[10]*m[15] - m[5]*m[11]*m[14] - m[9]*m[6]*m[15]
             + m[9]*m[7]*m[14] + m[13]*m[6]*m[11] - m[13]*m[7]*m[10];
    inv[4]  = -m[4]*m[10]*m[15] + m[4]*m[11]*m[14] + m[8]*m[6]*m[15]
             - m[8]*m[7]*m[14] - m[12]*m[6]*m[11] + m[12]*m[7]*m[10];
    inv[8]  =  m[4]*m[9]*m[15] - m[4]*m[11]*m[13] - m[8]*m[5]*m[15]
             + m[8]*m[7]*m[13] + m[12]*m[5]*m[11] - m[12]*m[7]*m[9];
    inv[12] = -m[4]*m[9]*m[14] + m[4]*m[10]*m[13] + m[8]*m[5]*m[14]
             - m[8]*m[6]*m[13] - m[12]*m[5]*m[10] + m[12]*m[6]*m[9];
    inv[1]  = -m[1]*m[10]*m[15] + m[1]*m[11]*m[14] + m[9]*m[2]*m[15]
             - m[9]*m[3]*m[14] - m[13]*m[2]*m[11] + m[13]*m[3]*m[10];
    inv[5]  =  m[0]*m[10]*m[15] - m[0]*m[11]*m[14] - m[8]*m[2]*m[15]
             + m[8]*m[3]*m[14] + m[12]*m[2]*m[11] - m[12]*m[3]*m[10];
    inv[9]  = -m[0]*m[9]*m[15] + m[0]*m[11]*m[13] + m[8]*m[1]*m[15]
             - m[8]*m[3]*m[13] - m[12]*m[1]*m[11] + m[12]*m[3]*m[9];
    inv[13] =  m[0]*m[9]*m[14] - m[0]*m[10]*m[13] - m[8]*m[1]*m[14]
             + m[8]*m[2]*m[13] + m[12]*m[1]*m[10] - m[12]*m[2]*m[9];
    inv[2]  =  m[1]*m[6]*m[15] - m[1]*m[7]*m[14] - m[5]*m[2]*m[15]
             + m[5]*m[3]*m[14] + m[13]*m[2]*m[7] - m[13]*m[3]*m[6];
    inv[6]  = -m[0]*m[6]*m[15] + m[0]*m[7]*m[14] + m[4]*m[2]*m[15]
             - m[4]*m[3]*m[14] - m[12]*m[2]*m[7] + m[12]*m[3]*m[6];
    inv[10] =  m[0]*m[5]*m[15] - m[0]*m[7]*m[13] - m[4]*m[1]*m[15]
             + m[4]*m[3]*m[13] + m[12]*m[1]*m[7] - m[12]*m[3]*m[5];
    inv[14] = -m[0]*m[5]*m[14] + m[0]*m[6]*m[13] + m[4]*m[1]*m[14]
             - m[4]*m[2]*m[13] - m[12]*m[1]*m[6] + m[12]*m[2]*m[5];
    inv[3]  = -m[1]*m[6]*m[11] + m[1]*m[7]*m[10] + m[5]*m[2]*m[11]
             - m[5]*m[3]*m[10] - m[9]*m[2]*m[7] + m[9]*m[3]*m[6];
    inv[7]  =  m[0]*m[6]*m[11] - m[0]*m[7]*m[10] - m[4]*m[2]*m[11]
             + m[4]*m[3]*m[10] + m[8]*m[2]*m[7] - m[8]*m[3]*m[6];
    inv[11] = -m[0]*m[5]*m[11] + m[0]*m[7]*m[9] + m[4]*m[1]*m[11]
             - m[4]*m[3]*m[9] - m[8]*m[1]*m[7] + m[8]*m[3]*m[5];
    inv[15] =  m[0]*m[5]*m[10] - m[0]*m[6]*m[9] - m[4]*m[1]*m[10]
             + m[4]*m[2]*m[9] + m[8]*m[1]*m[6] - m[8]*m[2]*m[5];
    const float det = m[0]*inv[0] + m[1]*inv[4] + m[2]*inv[8] + m[3]*inv[12];
    const float rdet = 1.0f / det;

    // M1 = Trig @ ref_v2r ; T = invF @ M1 ; rows 0..2 out
    float M1[4][4];
    for (int r = 0; r < 4; ++r)
        for (int c = 0; c < 4; ++c) {
            float s = 0.0f;
            for (int q = 0; q < 4; ++q) s += Trig[r][q] * ref_v2r[q * 4 + c];
            M1[r][c] = s;
        }
    for (int r = 0; r < 3; ++r)
        for (int c = 0; c < 4; ++c) {
            float s = 0.0f;
            for (int q = 0; q < 4; ++q) s += (inv[r * 4 + q] * rdet) * M1[q][c];
            Tout[r * 4 + c] = s;
        }
}

// ---------------------------------------------------------------------------
// Kernel 2: trilinear warp, IPT=8 voxels/thread, two-phase for MLP.
// R5 post-mortem: gather-latency bound (all pipes idle, VGPR=36 => compiler
// kept only 8 loads in flight). Phase A issues ALL 32 dwordx2 corner-pair
// loads (k-adjacent corners packed into one load) into a live array; phase B
// recomputes coordinates (bit-identical incremental arithmetic) and consumes
// in issue order. ~32 loads in flight per wave instead of 8, and half the
// gather instructions.
// ---------------------------------------------------------------------------
__global__ __launch_bounds__(256) void warp_kernel(
        const float* __restrict__ vol,
        const float* __restrict__ T,
        float* __restrict__ out) {
    // Wave-uniform scalar loads of the transform.
    const float t0 = T[0],  t1 = T[1],  t2  = T[2],  t3  = T[3];
    const float t4 = T[4],  t5 = T[5],  t6  = T[6],  t7  = T[7];
    const float t8 = T[8],  t9 = T[9],  t10 = T[10], t11 = T[11];

    // Brick mapping: xcd -> 2x2x2 brick of 128^3 (R3: FETCH 232->36 MB).
    const int bid = blockIdx.x;
    const int xcd = bid & 7;
    const int n = bid >> 3;          // 0..1023 per brick
    const int bi = (xcd >> 2) & 1;
    const int bj = (xcd >> 1) & 1;
    const int bk = xcd & 1;
    const int kt = n & 1;            // 2 k-tiles of 64
    const int jt = (n >> 1) & 31;    // 32 j-tiles of 4
    const int it = n >> 6;           // 16 i-tiles of IPT

    const int tx = threadIdx.x & 63; // k within tile (wave = contiguous k)
    const int ty = threadIdx.x >> 6; // j within tile

    const int i0 = (bi << 7) + it * IPT;
    const int j  = (bj << 7) + (jt << 2) + ty;
    const int k  = (bk << 7) + (kt << 6) + tx;

    const float gj = (float)j, gk = (float)k;
    const float di0 = t0 * (float)i0 + t1 * gj + t2  * gk + t3;
    const float dj0 = t4 * (float)i0 + t5 * gj + t6  * gk + t7;
    const float dk0 = t8 * (float)i0 + t9 * gj + t10 * gk + t11;

    // ---------------- Phase A: address calc + issue all loads ----------------
    f2v vv[IPT][4];
    {
        float di = di0, dj = dj0, dk = dk0;
#pragma unroll
        for (int s = 0; s < IPT; ++s) {
            const float cdi = fminf(fmaxf(di, 0.0f), (float)(DD - 1));
            const float cdj = fminf(fmaxf(dj, 0.0f), (float)(HH - 1));
            const float cdk = fminf(fmaxf(dk, 0.0f), (float)(WW - 1));

            const int fi = (int)cdi;
            const int fj = (int)cdj;
            const int fk = (int)cdk;
            const int ci = min(fi + 1, DD - 1);
            const int cj = min(fj + 1, HH - 1);
            const int pk = min(fk, WW - 2);   // pair base: [pk, pk+1]

            const int fi_o = fi << 16, ci_o = ci << 16;
            const int fj_o = fj << 8,  cj_o = cj << 8;

            vv[s][0] = *(const f2u*)(vol + (fi_o + fj_o + pk));
            vv[s][1] = *(const f2u*)(vol + (fi_o + cj_o + pk));
            vv[s][2] = *(const f2u*)(vol + (ci_o + fj_o + pk));
            vv[s][3] = *(const f2u*)(vol + (ci_o + cj_o + pk));

            di += t0; dj += t4; dk += t8;
        }
    }

    // ---------------- Phase B: weights, selects, lerp, store ----------------
    const int out_base = (i0 << 16) + (j << 8) + k;
    {
        float di = di0, dj = dj0, dk = dk0;
#pragma unroll
        for (int s = 0; s < IPT; ++s) {
            const bool ok = (di >= 0.0f) & (di <= (float)(DD - 1)) &
                            (dj >= 0.0f) & (dj <= (float)(HH - 1)) &
                            (dk >= 0.0f) & (dk <= (float)(WW - 1));

            const float cdi = fminf(fmaxf(di, 0.0f), (float)(DD - 1));
            const float cdj = fminf(fmaxf(dj, 0.0f), (float)(HH - 1));
            const float cdk = fminf(fmaxf(dk, 0.0f), (float)(WW - 1));

            const int fi = (int)cdi;
            const int fj = (int)cdj;
            const int fk = (int)cdk;

            const float wi = cdi - (float)fi;
            const float wj = cdj - (float)fj;
            const float wk = cdk - (float)fk;

            // k-edge select: when fk==255, pair base was 254 and the true
            // corner value (index 255) is .y; wk==0 there so v001 choice is
            // free — .y is correct in all cases.
            const bool hi = (fk == (WW - 1));
            const float v000 = hi ? vv[s][0].y : vv[s][0].x;
            const float v001 = vv[s][0].y;
            const float v010 = hi ? vv[s][1].y : vv[s][1].x;
            const float v011 = vv[s][1].y;
            const float v100 = hi ? vv[s][2].y : vv[s][2].x;
            const float v101 = vv[s][2].y;
            const float v110 = hi ? vv[s][3].y : vv[s][3].x;
            const float v111 = vv[s][3].y;

            const float c00 = v000 + (v001 - v000) * wk;
            const float c01 = v010 + (v011 - v010) * wk;
            const float c10 = v100 + (v101 - v100) * wk;
            const float c11 = v110 + (v111 - v110) * wk;
            const float c0  = c00 + (c01 - c00) * wj;
            const float c1  = c10 + (c11 - c10) * wj;
            const float val = c0 + (c1 - c0) * wi;

            __builtin_nontemporal_store(ok ? val : 0.0f,
                                        &out[out_base + (s << 16)]);

            di += t0; dj += t4; dk += t8;
        }
    }
}

extern "C" void kernel_launch(void* const* d_in, const int* in_sizes, int n_in,
                              void* d_out, int out_size, void* d_ws, size_t ws_size,
                              hipStream_t stream) {
    const float* image_targ  = (const float*)d_in[0];
    const float* angle       = (const float*)d_in[1];
    const float* translation = (const float*)d_in[2];
    const float* ref_v2r     = (const float*)d_in[3];
    const float* flo_v2r     = (const float*)d_in[4];
    const float* cog         = (const float*)d_in[5];
    float* out = (float*)d_out;
    float* Tws = (float*)d_ws;   // 12 floats

    compute_T_kernel<<<1, 64, 0, stream>>>(angle, translation, ref_v2r,
                                           flo_v2r, cog, Tws);
    warp_kernel<<<(DD * HH) / IPT, 256, 0, stream>>>(image_targ, Tws, out);
}